// Round 3
// baseline (257.503 us; speedup 1.0000x reference)
//
#include <hip/hip_runtime.h>
#include <hip/hip_bf16.h>

// EncoderLayer B=4,S=2048,D=512,H=8,HD=64,E=4. Inputs fp32, OUTPUT fp32.
// R15: flash_attn latency attack (was 4x above its 13.8us MFMA floor):
//  (a) deferred PV: PV(kt-1) executes inside iteration kt from registers
//      (paw) + long-staged V tile -> fills matrix pipe during K ds_read
//      latency; softmax(kt) no longer serializes against PV(kt).
//      V ring deepened to 4 buffers (read of tile t is in iter t+1).
//  (b) QK accumulator split st0/st1 -> dependent MFMA chain 4->2.
//  (c) XCD swizzle: each XCD owns 4 bh -> K/V working set 2MB/XCD fits L2
//      (was: all 32 bh = 16MB thrashing every 4MB L2).
// GEMMs/prep/transpose_v unchanged.

typedef __bf16 bf16;
typedef __attribute__((ext_vector_type(8))) __bf16 bf16x8;
typedef __attribute__((ext_vector_type(4))) __bf16 bf16x4;
typedef __attribute__((ext_vector_type(4))) float f32x4;
typedef __attribute__((ext_vector_type(16))) float f32x16;
typedef __attribute__((ext_vector_type(4))) short s16x4;
typedef __attribute__((ext_vector_type(2))) unsigned int u32x2;
typedef __attribute__((ext_vector_type(4))) unsigned int u32x4;

#define LOG2E 1.4426950408889634f
#define SCORE_SCALE 0.044194173824159216f /* 512^-0.5 (D^-0.25 on q AND k) */
#define SCALE_L2E (SCORE_SCALE * LOG2E)
#define FIXED_M 12.0f /* fixed softmax max; scores bounded, M-invariant */

#if __has_builtin(__builtin_amdgcn_exp2f)
#define EXP2(x) __builtin_amdgcn_exp2f(x)
#else
#define EXP2(x) exp2f(x)
#endif

__device__ __forceinline__ void gl_lds16(const bf16* g, bf16* l) {
  __builtin_amdgcn_global_load_lds(
      (const __attribute__((address_space(1))) unsigned int*)g,
      (__attribute__((address_space(3))) unsigned int*)l, 16, 0, 0);
}

__device__ __forceinline__ float gelu_tanh(float x) {
  float u = 0.7978845608028654f * (x + 0.044715f * x * x * x);
  float e = EXP2(u * (2.0f * LOG2E));   // e^(2u)
  float th = 1.0f - 2.0f / (e + 1.0f);  // tanh(u), saturates at +-1
  return 0.5f * x * (1.0f + th);
}

__device__ __forceinline__ f32x4 mfma_bf16(bf16x8 a, bf16x8 b, f32x4 c) {
  return __builtin_amdgcn_mfma_f32_16x16x32_bf16(a, b, c, 0, 0, 0);
}
__device__ __forceinline__ f32x16 mfma32x16(bf16x8 a, bf16x8 b, f32x16 c) {
  return __builtin_amdgcn_mfma_f32_32x32x16_bf16(a, b, c, 0, 0, 0);
}

// v_permlane32_swap_b32: vdst.hi32lanes <-> src.lo32lanes (writes BOTH).
__device__ __forceinline__ void plswap(unsigned int& a, unsigned int& b) {
  asm volatile("v_permlane32_swap_b32 %0, %1" : "+v"(a), "+v"(b));
}

// ---------------- GEMM: C[M,N] = A[M,K] @ Bt[N,K]^T (R11, unchanged) ------
template <int MODE, typename OutT, int TN>
__global__ __launch_bounds__(256, 2) void gemm_bt(
    const bf16* __restrict__ A, const bf16* __restrict__ Bt,
    OutT* __restrict__ C, const float* __restrict__ bias,
    const float* __restrict__ resf, const bf16* __restrict__ resb,
    int M, int N, int K) {
  constexpr int MI = (TN == 128) ? 4 : 2;
  __shared__ __align__(16) bf16 sA[2][128 * 32];
  __shared__ __align__(16) bf16 sB[2][TN * 32];
  const int tid = threadIdx.x;
  const int lane = tid & 63;
  const int quad = lane >> 4, lc = lane & 15;
  const int wave = tid >> 6;
  const int wr = (TN == 128) ? (wave >> 1) : wave;
  const int wc = (TN == 128) ? (wave & 1) : 0;
  const int m0 = blockIdx.y * 128, n0 = blockIdx.x * TN;

  const int srow = tid >> 2;
  const int kc = (tid & 3) * 8;
  const bf16* Ag1 = A + (size_t)(m0 + srow) * K + kc;
  const bf16* Ag2 = A + (size_t)(m0 + 64 + srow) * K + kc;
  const bf16* Bg1 = Bt + (size_t)(n0 + srow) * K + kc;
  const bf16* Bg2 = Bt + (size_t)(n0 + 64 + srow) * K + kc;
  const int o1 = tid * 8, o2 = (tid + 256) * 8;

  f32x4 acc[MI][4];
#pragma unroll
  for (int mi = 0; mi < MI; ++mi)
#pragma unroll
    for (int ni = 0; ni < 4; ++ni) acc[mi][ni] = (f32x4){0.f, 0.f, 0.f, 0.f};

  gl_lds16(Ag1, sA[0] + o1);
  gl_lds16(Ag2, sA[0] + o2);
  gl_lds16(Bg1, sB[0] + o1);
  if (TN == 128) gl_lds16(Bg2, sB[0] + o2);
  Ag1 += 32; Ag2 += 32; Bg1 += 32; Bg2 += 32;

  const int kIters = K >> 5;
  for (int kt = 0; kt < kIters; ++kt) {
    __syncthreads();
    const bf16* cA = sA[kt & 1];
    const bf16* cB = sB[kt & 1];
    if (kt + 1 < kIters) {
      bf16* nA = sA[(kt + 1) & 1];
      bf16* nB = sB[(kt + 1) & 1];
      gl_lds16(Ag1, nA + o1);
      gl_lds16(Ag2, nA + o2);
      gl_lds16(Bg1, nB + o1);
      if (TN == 128) gl_lds16(Bg2, nB + o2);
      Ag1 += 32; Ag2 += 32; Bg1 += 32; Bg2 += 32;
    }

    bf16x8 af[MI], bfm[4];
#pragma unroll
    for (int i = 0; i < MI; ++i)
      af[i] =
          *(const bf16x8*)(cA + ((wr * (16 * MI) + i * 16 + lc) * 32 + quad * 8));
#pragma unroll
    for (int i = 0; i < 4; ++i)
      bfm[i] = *(const bf16x8*)(cB + ((wc * 64 + i * 16 + lc) * 32 + quad * 8));
#pragma unroll
    for (int mi = 0; mi < MI; ++mi)
#pragma unroll
      for (int ni = 0; ni < 4; ++ni)
        acc[mi][ni] = mfma_bf16(af[mi], bfm[ni], acc[mi][ni]);
  }

#pragma unroll
  for (int mi = 0; mi < MI; ++mi) {
#pragma unroll
    for (int r = 0; r < 4; ++r) {
      const int row = m0 + wr * (16 * MI) + mi * 16 + quad * 4 + r;
#pragma unroll
      for (int ni = 0; ni < 4; ++ni) {
        const int col = n0 + wc * 64 + ni * 16 + lc;
        const size_t idx = (size_t)row * N + col;
        float v = acc[mi][ni][r];
        if (MODE == 1) v += resf[idx];
        if (MODE == 2) v = gelu_tanh(v + bias[col]);
        if (MODE == 3) v += bias[col] + (float)resb[idx];
        C[idx] = (OutT)v;
      }
    }
  }
}

// ---------------- flash attention (deferred-PV pipeline) -------------------
// grid (16, 32) raw; in-kernel XCD swizzle -> (qt, bh) with 4 bh per XCD.
// 4 waves/block, wave owns 32 q-rows. Per iteration kt:
//   barrier(vmcnt(4)) -> stage(kt+2) -> K/(QK MFMA, split acc) ->
//   PV(kt-1) from regs+old V buffer -> softmax(kt) -> paw.
// K ring = 3 buffers, V ring = 4 buffers (V of tile t is read in iter t+1;
// overwrite by stage(t+4), issued in iter t+2 after the barrier that
// ordered all t-reads -> race-free).
__global__ __launch_bounds__(256, 2) void flash_attn(
    const bf16* __restrict__ QKV, const bf16* __restrict__ Vt,
    bf16* __restrict__ O) {
  const int tid = threadIdx.x;
  const int lane = tid & 63, wave = tid >> 6;
  const int lo5 = lane & 31, hi = lane >> 5;
  // XCD swizzle: linear dispatch id -> xcd = id%8 (round-robin). Give each
  // XCD a contiguous group of 4 bh so K/V working set = 2MB <= 4MB L2.
  const int lin = blockIdx.y * 16 + blockIdx.x;
  const int xcd = lin & 7, slot = lin >> 3;
  const int bh = xcd * 4 + (slot >> 4);
  const int qt = slot & 15;
  const int b = bh >> 3, h = bh & 7;
  const int q0 = qt * 128 + wave * 32;

  __shared__ __align__(16) bf16 sK[3][4096];
  __shared__ __align__(16) bf16 sV[4][4096];

  // Q as B-operand: qf[i] holds Q[q0+lo5][i*16 + hi*8 + j]
  const bf16* Qrow = QKV + (size_t)(b * 2048 + q0 + lo5) * 1536 + h * 64;
  bf16x8 qf[4];
#pragma unroll
  for (int i = 0; i < 4; ++i) qf[i] = *(const bf16x8*)(Qrow + i * 16 + hi * 8);

  // staging: wave stages rows wave*16..+15; chunk swizzle pos^(row&7)
  const int colsw = (((lane & 7) ^ (lane >> 3)) << 3);
  const bf16* Kg0 = QKV + (size_t)b * 2048 * 1536 + 512 + (size_t)h * 64 +
                    (size_t)(wave * 16 + (lane >> 3)) * 1536 + colsw;
  const bf16* Vg0 = Vt + (size_t)bh * 64 * 2048 +
                    (size_t)(wave * 16 + (lane >> 3)) * 2048 + colsw;
  const int stag = wave * 1024;
  const int m7 = lo5 & 7;

  f32x16 oacc[2];
  oacc[0] = (f32x16)(0.f);
  oacc[1] = (f32x16)(0.f);
  float rsum = 0.f;

  auto stage = [&](int t) {
    bf16* dk = sK[t % 3] + stag;
    bf16* dv = sV[t & 3] + stag;
    gl_lds16(Kg0 + (size_t)t * 64 * 1536, dk);
    gl_lds16(Kg0 + (size_t)(t * 64 + 8) * 1536, dk + 512);
    gl_lds16(Vg0 + t * 64, dv);
    gl_lds16(Vg0 + t * 64 + 8 * 2048, dv + 512);
  };

  bf16x8 paw[4];  // P A-frags of the MOST RECENT tile (consumed next iter)

  // QK^T + softmax for tile kt from cK -> paw, rsum. Split accumulators.
  auto qk_softmax = [&](const bf16* cK) {
#pragma unroll
    for (int hl = 0; hl < 2; ++hl) {
      const int R = hl * 32 + lo5;
      bf16x8 kf0 = *(const bf16x8*)(cK + R * 64 + (((0 + hi) ^ m7) << 3));
      bf16x8 kf1 = *(const bf16x8*)(cK + R * 64 + (((2 + hi) ^ m7) << 3));
      bf16x8 kf2 = *(const bf16x8*)(cK + R * 64 + (((4 + hi) ^ m7) << 3));
      bf16x8 kf3 = *(const bf16x8*)(cK + R * 64 + (((6 + hi) ^ m7) << 3));
      f32x16 st0 = (f32x16)(0.f), st1 = (f32x16)(0.f);
      __builtin_amdgcn_s_setprio(1);
      st0 = mfma32x16(kf0, qf[0], st0);
      st1 = mfma32x16(kf1, qf[1], st1);
      st0 = mfma32x16(kf2, qf[2], st0);
      st1 = mfma32x16(kf3, qf[3], st1);
      __builtin_amdgcn_s_setprio(0);
      f32x16 st = st0 + st1;
      unsigned int q32[4][2];
#pragma unroll
      for (int g = 0; g < 4; ++g) {
        bf16x4 pb;
#pragma unroll
        for (int j = 0; j < 4; ++j) {
          float p = EXP2(st[4 * g + j] * SCALE_L2E - FIXED_M);
          rsum += p;
          pb[j] = (bf16)p;
        }
        u32x2 w2 = __builtin_bit_cast(u32x2, pb);
        q32[g][0] = w2[0];
        q32[g][1] = w2[1];
      }
#pragma unroll
      for (int t = 0; t < 2; ++t) {
        unsigned int a0 = q32[2 * t][0], a1 = q32[2 * t][1];
        unsigned int b0 = q32[2 * t + 1][0], b1 = q32[2 * t + 1][1];
        plswap(a0, b0);
        plswap(a1, b1);
        u32x4 f = {a0, a1, b0, b1};
        paw[hl * 2 + t] = __builtin_bit_cast(bf16x8, f);
      }
    }
  };

  // PV for the tile whose V lives in cV, P in paw.
  auto pv = [&](const bf16* cV) {
    __builtin_amdgcn_s_setprio(1);
#pragma unroll
    for (int dh = 0; dh < 2; ++dh) {
      const int Rd = dh * 32 + lo5;
#pragma unroll
      for (int w = 0; w < 4; ++w) {
        bf16x8 vf =
            *(const bf16x8*)(cV + Rd * 64 + (((2 * w + hi) ^ m7) << 3));
        oacc[dh] = mfma32x16(paw[w], vf, oacc[dh]);
      }
    }
    __builtin_amdgcn_s_setprio(0);
  };

  // prologue: tiles 0,1 in flight; process tile 0 (QK+softmax only)
  stage(0);
  stage(1);
  asm volatile("s_waitcnt vmcnt(4)\ns_barrier" ::: "memory");
  stage(2);
  qk_softmax(sK[0]);

  for (int kt = 1; kt < 32; ++kt) {
    // top of kt: outstanding = 8 (tiles kt, kt+1); drain oldest 4 (tile kt).
    if (kt == 31)
      asm volatile("s_waitcnt vmcnt(0)\ns_barrier" ::: "memory");
    else
      asm volatile("s_waitcnt vmcnt(4)\ns_barrier" ::: "memory");
    if (kt + 2 < 32) stage(kt + 2);
    const bf16* cK = sK[kt % 3];
    const bf16* cVp = sV[(kt + 3) & 3];  // V of tile kt-1
    // PV(kt-1) first: operands ready -> fills matrix pipe while K reads fly
    pv(cVp);
    qk_softmax(cK);
  }
  // epilogue: PV for tile 31
  pv(sV[31 & 3]);

  // combine row sums across hi halves; normalize; store
  rsum += __shfl_xor(rsum, 32, 64);
  const size_t obase = (size_t)(b * 2048 + q0) * 512 + h * 64;
#pragma unroll
  for (int r = 0; r < 16; ++r) {
    const int qloc = (r & 3) + 8 * (r >> 2) + 4 * hi;
    const float inv = 1.0f / __shfl(rsum, qloc, 64);
#pragma unroll
    for (int dh = 0; dh < 2; ++dh)
      O[obase + (size_t)qloc * 512 + dh * 32 + lo5] =
          (bf16)(oacc[dh][r] * inv);
  }
}

// ---------------- prep: convert x + all weight transposes ------------------
__global__ __launch_bounds__(256) void prep(
    const float* __restrict__ x, const float* __restrict__ Wq,
    const float* __restrict__ Wk, const float* __restrict__ Wv,
    const float* __restrict__ Wo, const float* __restrict__ W1,
    const float* __restrict__ W2, bf16* __restrict__ xb,
    bf16* __restrict__ WqkvT, bf16* __restrict__ WoT, bf16* __restrict__ W1T,
    bf16* __restrict__ W2T) {
  const int bid = blockIdx.x;
  if (bid < 4096) {
    const size_t i = ((size_t)bid * 256 + threadIdx.x) * 4;
    const float4 v = *(const float4*)(x + i);
    bf16x4 o;
    o[0] = (bf16)v.x; o[1] = (bf16)v.y; o[2] = (bf16)v.z; o[3] = (bf16)v.w;
    *(bf16x4*)(xb + i) = o;
    return;
  }
  const int t = bid - 4096;
  const float* in;
  bf16* out;
  int in_ld, out_ld, bx, by;
  if (t < 1024) {
    const int q = t >> 8, r = t & 255;
    bx = r & 15; by = r >> 4; in_ld = 512; out_ld = 512;
    in = (q == 0) ? Wq : (q == 1) ? Wk : (q == 2) ? Wv : Wo;
    out = (q == 0) ? WqkvT
          : (q == 1) ? WqkvT + 512 * 512
          : (q == 2) ? WqkvT + 2 * 512 * 512
                     : WoT;
  } else if (t < 2048) {
    const int r = t - 1024;
    bx = r & 63; by = r >> 6; in_ld = 2048; out_ld = 512;
    in = W1; out = W1T;
  } else {
    const int r = t - 2048;
    bx = r & 15; by = r >> 4; in_ld = 512; out_ld = 2048;
    in = W2; out = W2T;
  }
  __shared__ __align__(16) bf16 tl[32][33];
  const int tx = threadIdx.x & 31, ty = threadIdx.x >> 5;
  const int n0 = bx * 32, k0 = by * 32;
#pragma unroll
  for (int i = 0; i < 4; ++i)
    tl[ty + 8 * i][tx] = (bf16)in[(size_t)(k0 + ty + 8 * i) * in_ld + n0 + tx];
  __syncthreads();
#pragma unroll
  for (int i = 0; i < 4; ++i)
    out[(size_t)(n0 + ty + 8 * i) * out_ld + k0 + tx] = tl[tx][ty + 8 * i];
}

__global__ __launch_bounds__(256) void transpose_v(
    const bf16* __restrict__ QKV, bf16* __restrict__ Vt) {
  __shared__ __align__(16) bf16 t[32][33];
  const int tx = threadIdx.x & 31, ty = threadIdx.x >> 5;
  const int bh = blockIdx.z, b = bh >> 3, h = bh & 7;
  const bf16* ip = QKV + (size_t)b * 2048 * 1536 + 1024 + h * 64;
  bf16* op = Vt + (size_t)bh * 64 * 2048;
  const int d0 = blockIdx.x * 32, s0 = blockIdx.y * 32;
#pragma unroll
  for (int i = 0; i < 4; ++i)
    t[ty + 8 * i][tx] = ip[(size_t)(s0 + ty + 8 * i) * 1536 + d0 + tx];
  __syncthreads();
#pragma unroll
  for (int i = 0; i < 4; ++i)
    op[(size_t)(d0 + ty + 8 * i) * 2048 + s0 + tx] = t[tx][ty + 8 * i];
}

extern "C" void kernel_launch(void* const* d_in, const int* in_sizes, int n_in,
                              void* d_out, int out_size, void* d_ws,
                              size_t ws_size, hipStream_t stream) {
  const float* x = (const float*)d_in[0];
  const float* Wq = (const float*)d_in[1];
  const float* Wk = (const float*)d_in[2];
  const float* Wv = (const float*)d_in[3];
  const float* Wo = (const float*)d_in[4];
  const float* W1 = (const float*)d_in[5];
  const float* b1 = (const float*)d_in[6];
  const float* W2 = (const float*)d_in[7];
  const float* b2 = (const float*)d_in[8];
  float* out = (float*)d_out;  // fp32 output

  char* ws = (char*)d_ws;
  size_t off = 0;
  auto alloc = [&](size_t bytes) {
    char* p = ws + off;
    off += (bytes + 255) & ~(size_t)255;
    return p;
  };
  bf16* WqkvT = (bf16*)alloc(1536ULL * 512 * 2);
  bf16* WoT = (bf16*)alloc(512ULL * 512 * 2);
  bf16* W1T = (bf16*)alloc(2048ULL * 512 * 2);
  bf16* W2T = (bf16*)alloc(512ULL * 2048 * 2);
  bf16* xb = (bf16*)alloc(8192ULL * 512 * 2);      // bf16(x); reused as x2
  bf16* QKV = (bf16*)alloc(8192ULL * 1536 * 2);    // [8192][1536]
  bf16* Vt = (bf16*)alloc(32ULL * 64 * 2048 * 2);  // [B*H][64][2048]
  bf16* attn = (bf16*)alloc(8192ULL * 512 * 2);
  bf16* x2 = xb;     // xb dead after QKV gemm
  bf16* hbuf = QKV;  // FFN hidden [8192][2048] = QKV+Vt region (dead by FFN1)

  const dim3 tb(256);
  prep<<<dim3(7168), tb, 0, stream>>>(x, Wq, Wk, Wv, Wo, W1, W2, xb, WqkvT,
                                      WoT, W1T, W2T);
  gemm_bt<0, bf16, 128><<<dim3(12, 64), tb, 0, stream>>>(
      xb, WqkvT, QKV, nullptr, nullptr, nullptr, 8192, 1536, 512);
  transpose_v<<<dim3(2, 64, 32), tb, 0, stream>>>(QKV, Vt);
  flash_attn<<<dim3(16, 32), tb, 0, stream>>>(QKV, Vt, attn);
  gemm_bt<1, bf16, 64><<<dim3(8, 64), tb, 0, stream>>>(
      attn, WoT, x2, nullptr, x, nullptr, 8192, 512, 512);
  gemm_bt<2, bf16, 128><<<dim3(16, 64), tb, 0, stream>>>(
      x2, W1T, hbuf, b1, nullptr, nullptr, 8192, 2048, 512);
  gemm_bt<3, float, 64><<<dim3(8, 64), tb, 0, stream>>>(
      hbuf, W2T, out, b2, nullptr, x2, 8192, 512, 2048);
}

// Round 4
// 257.496 us; speedup vs baseline: 1.0000x; 1.0000x over previous
//
#include <hip/hip_runtime.h>
#include <hip/hip_bf16.h>

// EncoderLayer B=4,S=2048,D=512,H=8,HD=64,E=4. Inputs fp32, OUTPUT fp32.
// R16:
//  flash: revert R15's deferred-PV (regressed: kernel is latency-bound, not
//    HBM-bound); keep XCD swizzle (FETCH 69.7->12.4MB). R14 ordering +
//    (a) V fragments preloaded to regs BEFORE softmax (DS in-order return =>
//        PV MFMAs never wait on lgkm), (b) rsum split into 4 partials
//        (serial chain 128->32 cy/iter).
//  gemm_bt: 2-buffer __syncthreads (full vmcnt(0) drain per K-step) ->
//    3-buffer ring, prefetch distance 2, counted s_waitcnt vmcnt(L)+s_barrier
//    (R14-proven protocol). L=4 (TN=128) / 3 (TN=64).
// prep/transpose_v unchanged.

typedef __bf16 bf16;
typedef __attribute__((ext_vector_type(8))) __bf16 bf16x8;
typedef __attribute__((ext_vector_type(4))) __bf16 bf16x4;
typedef __attribute__((ext_vector_type(4))) float f32x4;
typedef __attribute__((ext_vector_type(16))) float f32x16;
typedef __attribute__((ext_vector_type(2))) unsigned int u32x2;
typedef __attribute__((ext_vector_type(4))) unsigned int u32x4;

#define LOG2E 1.4426950408889634f
#define SCORE_SCALE 0.044194173824159216f /* 512^-0.5 (D^-0.25 on q AND k) */
#define SCALE_L2E (SCORE_SCALE * LOG2E)
#define FIXED_M 12.0f /* fixed softmax max; scores bounded, M-invariant */

#if __has_builtin(__builtin_amdgcn_exp2f)
#define EXP2(x) __builtin_amdgcn_exp2f(x)
#else
#define EXP2(x) exp2f(x)
#endif

__device__ __forceinline__ void gl_lds16(const bf16* g, bf16* l) {
  __builtin_amdgcn_global_load_lds(
      (const __attribute__((address_space(1))) unsigned int*)g,
      (__attribute__((address_space(3))) unsigned int*)l, 16, 0, 0);
}

template <int N>
__device__ __forceinline__ void wait_vm_barrier() {
  if constexpr (N == 0)
    asm volatile("s_waitcnt vmcnt(0)\ns_barrier" ::: "memory");
  else if constexpr (N == 3)
    asm volatile("s_waitcnt vmcnt(3)\ns_barrier" ::: "memory");
  else if constexpr (N == 4)
    asm volatile("s_waitcnt vmcnt(4)\ns_barrier" ::: "memory");
}

__device__ __forceinline__ float gelu_tanh(float x) {
  float u = 0.7978845608028654f * (x + 0.044715f * x * x * x);
  float e = EXP2(u * (2.0f * LOG2E));   // e^(2u)
  float th = 1.0f - 2.0f / (e + 1.0f);  // tanh(u), saturates at +-1
  return 0.5f * x * (1.0f + th);
}

__device__ __forceinline__ f32x4 mfma_bf16(bf16x8 a, bf16x8 b, f32x4 c) {
  return __builtin_amdgcn_mfma_f32_16x16x32_bf16(a, b, c, 0, 0, 0);
}
__device__ __forceinline__ f32x16 mfma32x16(bf16x8 a, bf16x8 b, f32x16 c) {
  return __builtin_amdgcn_mfma_f32_32x32x16_bf16(a, b, c, 0, 0, 0);
}

// v_permlane32_swap_b32: vdst.hi32lanes <-> src.lo32lanes (writes BOTH).
__device__ __forceinline__ void plswap(unsigned int& a, unsigned int& b) {
  asm volatile("v_permlane32_swap_b32 %0, %1" : "+v"(a), "+v"(b));
}

// ---------------- GEMM: C[M,N] = A[M,K] @ Bt[N,K]^T ------------------------
// 3-buffer ring, distance-2 prefetch, counted vmcnt barrier (no full drain).
template <int MODE, typename OutT, int TN>
__global__ __launch_bounds__(256, 2) void gemm_bt(
    const bf16* __restrict__ A, const bf16* __restrict__ Bt,
    OutT* __restrict__ C, const float* __restrict__ bias,
    const float* __restrict__ resf, const bf16* __restrict__ resb,
    int M, int N, int K) {
  constexpr int MI = (TN == 128) ? 4 : 2;
  constexpr int L = (TN == 128) ? 4 : 3;  // gl_lds ops per tile
  __shared__ __align__(16) bf16 sA[3][128 * 32];
  __shared__ __align__(16) bf16 sB[3][TN * 32];
  const int tid = threadIdx.x;
  const int lane = tid & 63;
  const int quad = lane >> 4, lc = lane & 15;
  const int wave = tid >> 6;
  const int wr = (TN == 128) ? (wave >> 1) : wave;
  const int wc = (TN == 128) ? (wave & 1) : 0;
  const int m0 = blockIdx.y * 128, n0 = blockIdx.x * TN;

  const int srow = tid >> 2;
  const int kc = (tid & 3) * 8;
  const bf16* Ag1 = A + (size_t)(m0 + srow) * K + kc;
  const bf16* Ag2 = A + (size_t)(m0 + 64 + srow) * K + kc;
  const bf16* Bg1 = Bt + (size_t)(n0 + srow) * K + kc;
  const bf16* Bg2 = Bt + (size_t)(n0 + 64 + srow) * K + kc;
  const int o1 = tid * 8, o2 = (tid + 256) * 8;

  f32x4 acc[MI][4];
#pragma unroll
  for (int mi = 0; mi < MI; ++mi)
#pragma unroll
    for (int ni = 0; ni < 4; ++ni) acc[mi][ni] = (f32x4){0.f, 0.f, 0.f, 0.f};

  auto stage = [&](int t) {
    bf16* a = sA[t % 3];
    bf16* bb = sB[t % 3];
    gl_lds16(Ag1 + t * 32, a + o1);
    gl_lds16(Ag2 + t * 32, a + o2);
    gl_lds16(Bg1 + t * 32, bb + o1);
    if (TN == 128) gl_lds16(Bg2 + t * 32, bb + o2);
  };

  const int kIters = K >> 5;
  stage(0);
  stage(1);

  for (int kt = 0; kt < kIters; ++kt) {
    // top: outstanding = 2L (tiles kt, kt+1) steady / L at last iter.
    // Drain oldest L (tile kt); barrier publishes all waves' stripes.
    // ds_reads of buf (kt-1)%3 were all consumed by MFMAs (lgkm waits
    // emitted pre-consumption) before any wave reached this barrier, so
    // stage(kt+2)'s overwrite of that buffer is race-free.
    if (kt + 1 < kIters)
      wait_vm_barrier<L>();
    else
      wait_vm_barrier<0>();
    if (kt + 2 < kIters) stage(kt + 2);
    const bf16* cA = sA[kt % 3];
    const bf16* cB = sB[kt % 3];

    bf16x8 af[MI], bfm[4];
#pragma unroll
    for (int i = 0; i < MI; ++i)
      af[i] =
          *(const bf16x8*)(cA + ((wr * (16 * MI) + i * 16 + lc) * 32 + quad * 8));
#pragma unroll
    for (int i = 0; i < 4; ++i)
      bfm[i] = *(const bf16x8*)(cB + ((wc * 64 + i * 16 + lc) * 32 + quad * 8));
#pragma unroll
    for (int mi = 0; mi < MI; ++mi)
#pragma unroll
      for (int ni = 0; ni < 4; ++ni)
        acc[mi][ni] = mfma_bf16(af[mi], bfm[ni], acc[mi][ni]);
  }

#pragma unroll
  for (int mi = 0; mi < MI; ++mi) {
#pragma unroll
    for (int r = 0; r < 4; ++r) {
      const int row = m0 + wr * (16 * MI) + mi * 16 + quad * 4 + r;
#pragma unroll
      for (int ni = 0; ni < 4; ++ni) {
        const int col = n0 + wc * 64 + ni * 16 + lc;
        const size_t idx = (size_t)row * N + col;
        float v = acc[mi][ni][r];
        if (MODE == 1) v += resf[idx];
        if (MODE == 2) v = gelu_tanh(v + bias[col]);
        if (MODE == 3) v += bias[col] + (float)resb[idx];
        C[idx] = (OutT)v;
      }
    }
  }
}

// ---------------- flash attention (R14 order + V-preload + rsum split) -----
// grid (16, 32) raw; XCD swizzle: each XCD owns 4 bh (K/V 2MB, L2-resident).
// 4 waves/block, wave owns 32 q-rows. 3-ring K and V, distance-2 prefetch,
// counted vmcnt(4)+s_barrier.
__global__ __launch_bounds__(256, 2) void flash_attn(
    const bf16* __restrict__ QKV, const bf16* __restrict__ Vt,
    bf16* __restrict__ O) {
  const int tid = threadIdx.x;
  const int lane = tid & 63, wave = tid >> 6;
  const int lo5 = lane & 31, hi = lane >> 5;
  const int lin = blockIdx.y * 16 + blockIdx.x;
  const int xcd = lin & 7, slot = lin >> 3;
  const int bh = xcd * 4 + (slot >> 4);
  const int qt = slot & 15;
  const int b = bh >> 3, h = bh & 7;
  const int q0 = qt * 128 + wave * 32;

  __shared__ __align__(16) bf16 sK[3][4096];
  __shared__ __align__(16) bf16 sV[3][4096];

  // Q as B-operand: qf[i] holds Q[q0+lo5][i*16 + hi*8 + j]
  const bf16* Qrow = QKV + (size_t)(b * 2048 + q0 + lo5) * 1536 + h * 64;
  bf16x8 qf[4];
#pragma unroll
  for (int i = 0; i < 4; ++i) qf[i] = *(const bf16x8*)(Qrow + i * 16 + hi * 8);

  // staging: wave stages rows wave*16..+15; chunk swizzle pos^(row&7)
  const int colsw = (((lane & 7) ^ (lane >> 3)) << 3);
  const bf16* Kg0 = QKV + (size_t)b * 2048 * 1536 + 512 + (size_t)h * 64 +
                    (size_t)(wave * 16 + (lane >> 3)) * 1536 + colsw;
  const bf16* Vg0 = Vt + (size_t)bh * 64 * 2048 +
                    (size_t)(wave * 16 + (lane >> 3)) * 2048 + colsw;
  const int stag = wave * 1024;
  const int m7 = lo5 & 7;

  f32x16 oacc[2];
  oacc[0] = (f32x16)(0.f);
  oacc[1] = (f32x16)(0.f);
  float rs0 = 0.f, rs1 = 0.f, rs2 = 0.f, rs3 = 0.f;  // parallel rsum partials

  auto stage = [&](int t) {
    bf16* dk = sK[t % 3] + stag;
    bf16* dv = sV[t % 3] + stag;
    gl_lds16(Kg0 + (size_t)t * 64 * 1536, dk);
    gl_lds16(Kg0 + (size_t)(t * 64 + 8) * 1536, dk + 512);
    gl_lds16(Vg0 + t * 64, dv);
    gl_lds16(Vg0 + t * 64 + 8 * 2048, dv + 512);
  };
  stage(0);
  stage(1);  // 8 loads in flight

  for (int kt = 0; kt < 32; ++kt) {
    // Steady state: 8 outstanding (tiles kt, kt+1); drain oldest 4 (tile kt).
    // Own tile-kt loads done + barrier => ALL waves' tile-kt stripes done.
    // stage(kt+2) overwrites buffer (kt-1)%3, whose ds_reads all completed
    // (consumed by MFMAs) before this barrier in every wave.
    if (kt == 31)
      wait_vm_barrier<0>();
    else
      wait_vm_barrier<4>();
    if (kt + 2 < 32) stage(kt + 2);
    const bf16* cK = sK[kt % 3];
    const bf16* cV = sV[kt % 3];

    // Preload ALL V fragments first. DS ops return in-order, so any later
    // wait on K fragments implies these are complete -> PV never stalls.
    bf16x8 vf[2][4];
#pragma unroll
    for (int dh = 0; dh < 2; ++dh) {
      const int Rd = dh * 32 + lo5;
#pragma unroll
      for (int w = 0; w < 4; ++w)
        vf[dh][w] =
            *(const bf16x8*)(cV + Rd * 64 + (((2 * w + hi) ^ m7) << 3));
    }

    bf16x8 paw[4];  // x16 A-frags; window w covers s in [16*w, 16*w+16)
#pragma unroll
    for (int hl = 0; hl < 2; ++hl) {
      // S^T 32x32 tile: rows s = hl*32+.., cols q
      f32x16 st = (f32x16)(0.f);
      const int R = hl * 32 + lo5;
      __builtin_amdgcn_s_setprio(1);
#pragma unroll
      for (int i = 0; i < 4; ++i) {
        bf16x8 kf =
            *(const bf16x8*)(cK + R * 64 + (((2 * i + hi) ^ m7) << 3));
        st = mfma32x16(kf, qf[i], st);
      }
      __builtin_amdgcn_s_setprio(0);
      // p = exp2(raw*scale - M); partial sums by j; quads as u32 pairs
      unsigned int q32[4][2];
#pragma unroll
      for (int g = 0; g < 4; ++g) {
        bf16x4 pb;
        float p0 = EXP2(st[4 * g + 0] * SCALE_L2E - FIXED_M);
        float p1 = EXP2(st[4 * g + 1] * SCALE_L2E - FIXED_M);
        float p2 = EXP2(st[4 * g + 2] * SCALE_L2E - FIXED_M);
        float p3 = EXP2(st[4 * g + 3] * SCALE_L2E - FIXED_M);
        rs0 += p0; rs1 += p1; rs2 += p2; rs3 += p3;
        pb[0] = (bf16)p0; pb[1] = (bf16)p1; pb[2] = (bf16)p2; pb[3] = (bf16)p3;
        u32x2 w2 = __builtin_bit_cast(u32x2, pb);
        q32[g][0] = w2[0];
        q32[g][1] = w2[1];
      }
      // x16 A-frags via one hi<->lo swap per u32 pair (see R14 derivation)
#pragma unroll
      for (int t = 0; t < 2; ++t) {
        unsigned int a0 = q32[2 * t][0], a1 = q32[2 * t][1];
        unsigned int b0 = q32[2 * t + 1][0], b1 = q32[2 * t + 1][1];
        plswap(a0, b0);
        plswap(a1, b1);
        u32x4 f = {a0, a1, b0, b1};
        paw[hl * 2 + t] = __builtin_bit_cast(bf16x8, f);
      }
    }

    // PV: O[q][d] += P.V from registers, full-rate x16 MFMA
    __builtin_amdgcn_s_setprio(1);
#pragma unroll
    for (int dh = 0; dh < 2; ++dh)
#pragma unroll
      for (int w = 0; w < 4; ++w)
        oacc[dh] = mfma32x16(paw[w], vf[dh][w], oacc[dh]);
    __builtin_amdgcn_s_setprio(0);
  }

  // combine row sums across hi halves; normalize; store
  float rsum = (rs0 + rs1) + (rs2 + rs3);
  rsum += __shfl_xor(rsum, 32, 64);
  const size_t obase = (size_t)(b * 2048 + q0) * 512 + h * 64;
#pragma unroll
  for (int r = 0; r < 16; ++r) {
    const int qloc = (r & 3) + 8 * (r >> 2) + 4 * hi;
    const float inv = 1.0f / __shfl(rsum, qloc, 64);
#pragma unroll
    for (int dh = 0; dh < 2; ++dh)
      O[obase + (size_t)qloc * 512 + dh * 32 + lo5] =
          (bf16)(oacc[dh][r] * inv);
  }
}

// ---------------- prep: convert x + all weight transposes ------------------
__global__ __launch_bounds__(256) void prep(
    const float* __restrict__ x, const float* __restrict__ Wq,
    const float* __restrict__ Wk, const float* __restrict__ Wv,
    const float* __restrict__ Wo, const float* __restrict__ W1,
    const float* __restrict__ W2, bf16* __restrict__ xb,
    bf16* __restrict__ WqkvT, bf16* __restrict__ WoT, bf16* __restrict__ W1T,
    bf16* __restrict__ W2T) {
  const int bid = blockIdx.x;
  if (bid < 4096) {
    const size_t i = ((size_t)bid * 256 + threadIdx.x) * 4;
    const float4 v = *(const float4*)(x + i);
    bf16x4 o;
    o[0] = (bf16)v.x; o[1] = (bf16)v.y; o[2] = (bf16)v.z; o[3] = (bf16)v.w;
    *(bf16x4*)(xb + i) = o;
    return;
  }
  const int t = bid - 4096;
  const float* in;
  bf16* out;
  int in_ld, out_ld, bx, by;
  if (t < 1024) {
    const int q = t >> 8, r = t & 255;
    bx = r & 15; by = r >> 4; in_ld = 512; out_ld = 512;
    in = (q == 0) ? Wq : (q == 1) ? Wk : (q == 2) ? Wv : Wo;
    out = (q == 0) ? WqkvT
          : (q == 1) ? WqkvT + 512 * 512
          : (q == 2) ? WqkvT + 2 * 512 * 512
                     : WoT;
  } else if (t < 2048) {
    const int r = t - 1024;
    bx = r & 63; by = r >> 6; in_ld = 2048; out_ld = 512;
    in = W1; out = W1T;
  } else {
    const int r = t - 2048;
    bx = r & 15; by = r >> 4; in_ld = 512; out_ld = 2048;
    in = W2; out = W2T;
  }
  __shared__ __align__(16) bf16 tl[32][33];
  const int tx = threadIdx.x & 31, ty = threadIdx.x >> 5;
  const int n0 = bx * 32, k0 = by * 32;
#pragma unroll
  for (int i = 0; i < 4; ++i)
    tl[ty + 8 * i][tx] = (bf16)in[(size_t)(k0 + ty + 8 * i) * in_ld + n0 + tx];
  __syncthreads();
#pragma unroll
  for (int i = 0; i < 4; ++i)
    out[(size_t)(n0 + ty + 8 * i) * out_ld + k0 + tx] = tl[tx][ty + 8 * i];
}

__global__ __launch_bounds__(256) void transpose_v(
    const bf16* __restrict__ QKV, bf16* __restrict__ Vt) {
  __shared__ __align__(16) bf16 t[32][33];
  const int tx = threadIdx.x & 31, ty = threadIdx.x >> 5;
  const int bh = blockIdx.z, b = bh >> 3, h = bh & 7;
  const bf16* ip = QKV + (size_t)b * 2048 * 1536 + 1024 + h * 64;
  bf16* op = Vt + (size_t)bh * 64 * 2048;
  const int d0 = blockIdx.x * 32, s0 = blockIdx.y * 32;
#pragma unroll
  for (int i = 0; i < 4; ++i)
    t[ty + 8 * i][tx] = ip[(size_t)(s0 + ty + 8 * i) * 1536 + d0 + tx];
  __syncthreads();
#pragma unroll
  for (int i = 0; i < 4; ++i)
    op[(size_t)(d0 + ty + 8 * i) * 2048 + s0 + tx] = t[tx][ty + 8 * i];
}

extern "C" void kernel_launch(void* const* d_in, const int* in_sizes, int n_in,
                              void* d_out, int out_size, void* d_ws,
                              size_t ws_size, hipStream_t stream) {
  const float* x = (const float*)d_in[0];
  const float* Wq = (const float*)d_in[1];
  const float* Wk = (const float*)d_in[2];
  const float* Wv = (const float*)d_in[3];
  const float* Wo = (const float*)d_in[4];
  const float* W1 = (const float*)d_in[5];
  const float* b1 = (const float*)d_in[6];
  const float* W2 = (const float*)d_in[7];
  const float* b2 = (const float*)d_in[8];
  float* out = (float*)d_out;  // fp32 output

  char* ws = (char*)d_ws;
  size_t off = 0;
  auto alloc = [&](size_t bytes) {
    char* p = ws + off;
    off += (bytes + 255) & ~(size_t)255;
    return p;
  };
  bf16* WqkvT = (bf16*)alloc(1536ULL * 512 * 2);
  bf16* WoT = (bf16*)alloc(512ULL * 512 * 2);
  bf16* W1T = (bf16*)alloc(2048ULL * 512 * 2);
  bf16* W2T = (bf16*)alloc(512ULL * 2048 * 2);
  bf16* xb = (bf16*)alloc(8192ULL * 512 * 2);      // bf16(x); reused as x2
  bf16* QKV = (bf16*)alloc(8192ULL * 1536 * 2);    // [8192][1536]
  bf16* Vt = (bf16*)alloc(32ULL * 64 * 2048 * 2);  // [B*H][64][2048]
  bf16* attn = (bf16*)alloc(8192ULL * 512 * 2);
  bf16* x2 = xb;     // xb dead after QKV gemm
  bf16* hbuf = QKV;  // FFN hidden [8192][2048] = QKV+Vt region (dead by FFN1)

  const dim3 tb(256);
  prep<<<dim3(7168), tb, 0, stream>>>(x, Wq, Wk, Wv, Wo, W1, W2, xb, WqkvT,
                                      WoT, W1T, W2T);
  gemm_bt<0, bf16, 128><<<dim3(12, 64), tb, 0, stream>>>(
      xb, WqkvT, QKV, nullptr, nullptr, nullptr, 8192, 1536, 512);
  transpose_v<<<dim3(2, 64, 32), tb, 0, stream>>>(QKV, Vt);
  flash_attn<<<dim3(16, 32), tb, 0, stream>>>(QKV, Vt, attn);
  gemm_bt<1, bf16, 64><<<dim3(8, 64), tb, 0, stream>>>(
      attn, WoT, x2, nullptr, x, nullptr, 8192, 512, 512);
  gemm_bt<2, bf16, 128><<<dim3(16, 64), tb, 0, stream>>>(
      x2, W1T, hbuf, b1, nullptr, nullptr, 8192, 2048, 512);
  gemm_bt<3, float, 64><<<dim3(8, 64), tb, 0, stream>>>(
      hbuf, W2T, out, b2, nullptr, x2, 8192, 512, 2048);
}

// Round 5
// 247.017 us; speedup vs baseline: 1.0424x; 1.0424x over previous
//
#include <hip/hip_runtime.h>
#include <hip/hip_bf16.h>

// EncoderLayer B=4,S=2048,D=512,H=8,HD=64,E=4. Inputs fp32, OUTPUT fp32.
// R17:
//  - TN=128 GEMMs (QKV, FFN1) reverted to R11 2-buffer __syncthreads (R16's
//    3-ring cost 48KB LDS -> occupancy 4->3 blocks/CU and regressed FFN1
//    61 vs <=56; latency-bound kernel values TLP over drain removal).
//  - TN=64 GEMMs (Wo, FFN2) keep 3-ring counted vmcnt(3) (36KB fits 4/CU).
//  - transpose_v FUSED into QKV-GEMM epilogue: V column-blocks (n0>=1024,
//    uniform branch) store transposed straight to Vt (8B bf16x4 per thread,
//    4 consecutive s at fixed d). Kernel + 16.8MB traffic eliminated.
//  - flash unchanged from R16 (XCD swizzle + V-preload + rsum split).

typedef __bf16 bf16;
typedef __attribute__((ext_vector_type(8))) __bf16 bf16x8;
typedef __attribute__((ext_vector_type(4))) __bf16 bf16x4;
typedef __attribute__((ext_vector_type(4))) float f32x4;
typedef __attribute__((ext_vector_type(16))) float f32x16;
typedef __attribute__((ext_vector_type(2))) unsigned int u32x2;
typedef __attribute__((ext_vector_type(4))) unsigned int u32x4;

#define LOG2E 1.4426950408889634f
#define SCORE_SCALE 0.044194173824159216f /* 512^-0.5 (D^-0.25 on q AND k) */
#define SCALE_L2E (SCORE_SCALE * LOG2E)
#define FIXED_M 12.0f /* fixed softmax max; scores bounded, M-invariant */

#if __has_builtin(__builtin_amdgcn_exp2f)
#define EXP2(x) __builtin_amdgcn_exp2f(x)
#else
#define EXP2(x) exp2f(x)
#endif

__device__ __forceinline__ void gl_lds16(const bf16* g, bf16* l) {
  __builtin_amdgcn_global_load_lds(
      (const __attribute__((address_space(1))) unsigned int*)g,
      (__attribute__((address_space(3))) unsigned int*)l, 16, 0, 0);
}

template <int N>
__device__ __forceinline__ void wait_vm_barrier() {
  if constexpr (N == 0)
    asm volatile("s_waitcnt vmcnt(0)\ns_barrier" ::: "memory");
  else if constexpr (N == 3)
    asm volatile("s_waitcnt vmcnt(3)\ns_barrier" ::: "memory");
  else if constexpr (N == 4)
    asm volatile("s_waitcnt vmcnt(4)\ns_barrier" ::: "memory");
}

__device__ __forceinline__ float gelu_tanh(float x) {
  float u = 0.7978845608028654f * (x + 0.044715f * x * x * x);
  float e = EXP2(u * (2.0f * LOG2E));   // e^(2u)
  float th = 1.0f - 2.0f / (e + 1.0f);  // tanh(u), saturates at +-1
  return 0.5f * x * (1.0f + th);
}

__device__ __forceinline__ f32x4 mfma_bf16(bf16x8 a, bf16x8 b, f32x4 c) {
  return __builtin_amdgcn_mfma_f32_16x16x32_bf16(a, b, c, 0, 0, 0);
}
__device__ __forceinline__ f32x16 mfma32x16(bf16x8 a, bf16x8 b, f32x16 c) {
  return __builtin_amdgcn_mfma_f32_32x32x16_bf16(a, b, c, 0, 0, 0);
}

// v_permlane32_swap_b32: vdst.hi32lanes <-> src.lo32lanes (writes BOTH).
__device__ __forceinline__ void plswap(unsigned int& a, unsigned int& b) {
  asm volatile("v_permlane32_swap_b32 %0, %1" : "+v"(a), "+v"(b));
}

// ---------------- GEMM: C[M,N] = A[M,K] @ Bt[N,K]^T ------------------------
// TN=128: 2-buffer __syncthreads (R11 proven, 32KB, 4-5 blocks/CU).
// TN=64 : 3-ring counted vmcnt(3) (36KB, 4 blocks/CU).
// MODE 0 additionally writes the V panel (n0>=1024) transposed into vt.
template <int MODE, typename OutT, int TN>
__global__ __launch_bounds__(256, 2) void gemm_bt(
    const bf16* __restrict__ A, const bf16* __restrict__ Bt,
    OutT* __restrict__ C, const float* __restrict__ bias,
    const float* __restrict__ resf, const bf16* __restrict__ resb,
    bf16* __restrict__ vt, int M, int N, int K) {
  constexpr int MI = (TN == 128) ? 4 : 2;
  constexpr int NBUF = (TN == 128) ? 2 : 3;
  __shared__ __align__(16) bf16 sA[NBUF][128 * 32];
  __shared__ __align__(16) bf16 sB[NBUF][TN * 32];
  const int tid = threadIdx.x;
  const int lane = tid & 63;
  const int quad = lane >> 4, lc = lane & 15;
  const int wave = tid >> 6;
  const int wr = (TN == 128) ? (wave >> 1) : wave;
  const int wc = (TN == 128) ? (wave & 1) : 0;
  const int m0 = blockIdx.y * 128, n0 = blockIdx.x * TN;

  const int srow = tid >> 2;
  const int kc = (tid & 3) * 8;
  const bf16* Ag1 = A + (size_t)(m0 + srow) * K + kc;
  const bf16* Ag2 = A + (size_t)(m0 + 64 + srow) * K + kc;
  const bf16* Bg1 = Bt + (size_t)(n0 + srow) * K + kc;
  const bf16* Bg2 = Bt + (size_t)(n0 + 64 + srow) * K + kc;
  const int o1 = tid * 8, o2 = (tid + 256) * 8;

  f32x4 acc[MI][4];
#pragma unroll
  for (int mi = 0; mi < MI; ++mi)
#pragma unroll
    for (int ni = 0; ni < 4; ++ni) acc[mi][ni] = (f32x4){0.f, 0.f, 0.f, 0.f};

  const int kIters = K >> 5;

  if constexpr (TN == 128) {
    // ---- 2-buffer __syncthreads (R11) ----
    gl_lds16(Ag1, sA[0] + o1);
    gl_lds16(Ag2, sA[0] + o2);
    gl_lds16(Bg1, sB[0] + o1);
    gl_lds16(Bg2, sB[0] + o2);
    Ag1 += 32; Ag2 += 32; Bg1 += 32; Bg2 += 32;

    for (int kt = 0; kt < kIters; ++kt) {
      __syncthreads();
      const bf16* cA = sA[kt & 1];
      const bf16* cB = sB[kt & 1];
      if (kt + 1 < kIters) {
        bf16* nA = sA[(kt + 1) & 1];
        bf16* nB = sB[(kt + 1) & 1];
        gl_lds16(Ag1, nA + o1);
        gl_lds16(Ag2, nA + o2);
        gl_lds16(Bg1, nB + o1);
        gl_lds16(Bg2, nB + o2);
        Ag1 += 32; Ag2 += 32; Bg1 += 32; Bg2 += 32;
      }
      bf16x8 af[MI], bfm[4];
#pragma unroll
      for (int i = 0; i < MI; ++i)
        af[i] = *(const bf16x8*)(cA +
                                 ((wr * 64 + i * 16 + lc) * 32 + quad * 8));
#pragma unroll
      for (int i = 0; i < 4; ++i)
        bfm[i] =
            *(const bf16x8*)(cB + ((wc * 64 + i * 16 + lc) * 32 + quad * 8));
#pragma unroll
      for (int mi = 0; mi < MI; ++mi)
#pragma unroll
        for (int ni = 0; ni < 4; ++ni)
          acc[mi][ni] = mfma_bf16(af[mi], bfm[ni], acc[mi][ni]);
    }
  } else {
    // ---- 3-ring counted vmcnt(3) (R16) ----
    auto stage = [&](int t) {
      bf16* a = sA[t % 3];
      bf16* bb = sB[t % 3];
      gl_lds16(Ag1 + t * 32, a + o1);
      gl_lds16(Ag2 + t * 32, a + o2);
      gl_lds16(Bg1 + t * 32, bb + o1);
    };
    stage(0);
    stage(1);
    for (int kt = 0; kt < kIters; ++kt) {
      if (kt + 1 < kIters)
        wait_vm_barrier<3>();
      else
        wait_vm_barrier<0>();
      if (kt + 2 < kIters) stage(kt + 2);
      const bf16* cA = sA[kt % 3];
      const bf16* cB = sB[kt % 3];
      bf16x8 af[MI], bfm[4];
#pragma unroll
      for (int i = 0; i < MI; ++i)
        af[i] = *(const bf16x8*)(cA +
                                 ((wr * 32 + i * 16 + lc) * 32 + quad * 8));
#pragma unroll
      for (int i = 0; i < 4; ++i)
        bfm[i] = *(const bf16x8*)(cB + ((i * 16 + lc) * 32 + quad * 8));
#pragma unroll
      for (int mi = 0; mi < MI; ++mi)
#pragma unroll
        for (int ni = 0; ni < 4; ++ni)
          acc[mi][ni] = mfma_bf16(af[mi], bfm[ni], acc[mi][ni]);
    }
  }

  // ---------------- epilogue ----------------
  if constexpr (MODE == 0) {
    if (n0 >= 1024) {
      // V panel: write transposed into Vt[(b*8+h)][d][s]
#pragma unroll
      for (int mi = 0; mi < MI; ++mi) {
        const int row0 = m0 + wr * (16 * MI) + mi * 16 + quad * 4;
        const int bb = row0 >> 11, s0 = row0 & 2047;
#pragma unroll
        for (int ni = 0; ni < 4; ++ni) {
          const int col = n0 + wc * 64 + ni * 16 + lc;  // 1024..1535
          const int hh = (col >> 6) & 7, d = col & 63;
          bf16x4 pb;
#pragma unroll
          for (int r = 0; r < 4; ++r) pb[r] = (bf16)acc[mi][ni][r];
          *(bf16x4*)(vt + ((size_t)((bb * 8 + hh) * 64 + d)) * 2048 + s0) = pb;
        }
      }
      return;
    }
  }
#pragma unroll
  for (int mi = 0; mi < MI; ++mi) {
#pragma unroll
    for (int r = 0; r < 4; ++r) {
      const int row = m0 + wr * (16 * MI) + mi * 16 + quad * 4 + r;
#pragma unroll
      for (int ni = 0; ni < 4; ++ni) {
        const int col = n0 + wc * 64 + ni * 16 + lc;
        const size_t idx = (size_t)row * N + col;
        float v = acc[mi][ni][r];
        if (MODE == 1) v += resf[idx];
        if (MODE == 2) v = gelu_tanh(v + bias[col]);
        if (MODE == 3) v += bias[col] + (float)resb[idx];
        C[idx] = (OutT)v;
      }
    }
  }
}

// ---------------- flash attention (R16, unchanged) -------------------------
// grid (16, 32) raw; XCD swizzle: each XCD owns 4 bh (K/V 2MB, L2-resident).
// 4 waves/block, wave owns 32 q-rows. 3-ring K and V, distance-2 prefetch,
// counted vmcnt(4)+s_barrier. V fragments preloaded before softmax.
__global__ __launch_bounds__(256, 2) void flash_attn(
    const bf16* __restrict__ QKV, const bf16* __restrict__ Vt,
    bf16* __restrict__ O) {
  const int tid = threadIdx.x;
  const int lane = tid & 63, wave = tid >> 6;
  const int lo5 = lane & 31, hi = lane >> 5;
  const int lin = blockIdx.y * 16 + blockIdx.x;
  const int xcd = lin & 7, slot = lin >> 3;
  const int bh = xcd * 4 + (slot >> 4);
  const int qt = slot & 15;
  const int b = bh >> 3, h = bh & 7;
  const int q0 = qt * 128 + wave * 32;

  __shared__ __align__(16) bf16 sK[3][4096];
  __shared__ __align__(16) bf16 sV[3][4096];

  // Q as B-operand: qf[i] holds Q[q0+lo5][i*16 + hi*8 + j]
  const bf16* Qrow = QKV + (size_t)(b * 2048 + q0 + lo5) * 1536 + h * 64;
  bf16x8 qf[4];
#pragma unroll
  for (int i = 0; i < 4; ++i) qf[i] = *(const bf16x8*)(Qrow + i * 16 + hi * 8);

  // staging: wave stages rows wave*16..+15; chunk swizzle pos^(row&7)
  const int colsw = (((lane & 7) ^ (lane >> 3)) << 3);
  const bf16* Kg0 = QKV + (size_t)b * 2048 * 1536 + 512 + (size_t)h * 64 +
                    (size_t)(wave * 16 + (lane >> 3)) * 1536 + colsw;
  const bf16* Vg0 = Vt + (size_t)bh * 64 * 2048 +
                    (size_t)(wave * 16 + (lane >> 3)) * 2048 + colsw;
  const int stag = wave * 1024;
  const int m7 = lo5 & 7;

  f32x16 oacc[2];
  oacc[0] = (f32x16)(0.f);
  oacc[1] = (f32x16)(0.f);
  float rs0 = 0.f, rs1 = 0.f, rs2 = 0.f, rs3 = 0.f;  // parallel rsum partials

  auto stage = [&](int t) {
    bf16* dk = sK[t % 3] + stag;
    bf16* dv = sV[t % 3] + stag;
    gl_lds16(Kg0 + (size_t)t * 64 * 1536, dk);
    gl_lds16(Kg0 + (size_t)(t * 64 + 8) * 1536, dk + 512);
    gl_lds16(Vg0 + t * 64, dv);
    gl_lds16(Vg0 + t * 64 + 8 * 2048, dv + 512);
  };
  stage(0);
  stage(1);  // 8 loads in flight

  for (int kt = 0; kt < 32; ++kt) {
    if (kt == 31)
      wait_vm_barrier<0>();
    else
      wait_vm_barrier<4>();
    if (kt + 2 < 32) stage(kt + 2);
    const bf16* cK = sK[kt % 3];
    const bf16* cV = sV[kt % 3];

    // Preload ALL V fragments first (DS in-order => PV never waits on lgkm).
    bf16x8 vf[2][4];
#pragma unroll
    for (int dh = 0; dh < 2; ++dh) {
      const int Rd = dh * 32 + lo5;
#pragma unroll
      for (int w = 0; w < 4; ++w)
        vf[dh][w] =
            *(const bf16x8*)(cV + Rd * 64 + (((2 * w + hi) ^ m7) << 3));
    }

    bf16x8 paw[4];  // x16 A-frags; window w covers s in [16*w, 16*w+16)
#pragma unroll
    for (int hl = 0; hl < 2; ++hl) {
      f32x16 st = (f32x16)(0.f);
      const int R = hl * 32 + lo5;
      __builtin_amdgcn_s_setprio(1);
#pragma unroll
      for (int i = 0; i < 4; ++i) {
        bf16x8 kf =
            *(const bf16x8*)(cK + R * 64 + (((2 * i + hi) ^ m7) << 3));
        st = mfma32x16(kf, qf[i], st);
      }
      __builtin_amdgcn_s_setprio(0);
      unsigned int q32[4][2];
#pragma unroll
      for (int g = 0; g < 4; ++g) {
        bf16x4 pb;
        float p0 = EXP2(st[4 * g + 0] * SCALE_L2E - FIXED_M);
        float p1 = EXP2(st[4 * g + 1] * SCALE_L2E - FIXED_M);
        float p2 = EXP2(st[4 * g + 2] * SCALE_L2E - FIXED_M);
        float p3 = EXP2(st[4 * g + 3] * SCALE_L2E - FIXED_M);
        rs0 += p0; rs1 += p1; rs2 += p2; rs3 += p3;
        pb[0] = (bf16)p0; pb[1] = (bf16)p1; pb[2] = (bf16)p2; pb[3] = (bf16)p3;
        u32x2 w2 = __builtin_bit_cast(u32x2, pb);
        q32[g][0] = w2[0];
        q32[g][1] = w2[1];
      }
#pragma unroll
      for (int t = 0; t < 2; ++t) {
        unsigned int a0 = q32[2 * t][0], a1 = q32[2 * t][1];
        unsigned int b0 = q32[2 * t + 1][0], b1 = q32[2 * t + 1][1];
        plswap(a0, b0);
        plswap(a1, b1);
        u32x4 f = {a0, a1, b0, b1};
        paw[hl * 2 + t] = __builtin_bit_cast(bf16x8, f);
      }
    }

    // PV: O[q][d] += P.V from registers, full-rate x16 MFMA
    __builtin_amdgcn_s_setprio(1);
#pragma unroll
    for (int dh = 0; dh < 2; ++dh)
#pragma unroll
      for (int w = 0; w < 4; ++w)
        oacc[dh] = mfma32x16(paw[w], vf[dh][w], oacc[dh]);
    __builtin_amdgcn_s_setprio(0);
  }

  // combine row sums across hi halves; normalize; store
  float rsum = (rs0 + rs1) + (rs2 + rs3);
  rsum += __shfl_xor(rsum, 32, 64);
  const size_t obase = (size_t)(b * 2048 + q0) * 512 + h * 64;
#pragma unroll
  for (int r = 0; r < 16; ++r) {
    const int qloc = (r & 3) + 8 * (r >> 2) + 4 * hi;
    const float inv = 1.0f / __shfl(rsum, qloc, 64);
#pragma unroll
    for (int dh = 0; dh < 2; ++dh)
      O[obase + (size_t)qloc * 512 + dh * 32 + lo5] =
          (bf16)(oacc[dh][r] * inv);
  }
}

// ---------------- prep: convert x + all weight transposes ------------------
__global__ __launch_bounds__(256) void prep(
    const float* __restrict__ x, const float* __restrict__ Wq,
    const float* __restrict__ Wk, const float* __restrict__ Wv,
    const float* __restrict__ Wo, const float* __restrict__ W1,
    const float* __restrict__ W2, bf16* __restrict__ xb,
    bf16* __restrict__ WqkvT, bf16* __restrict__ WoT, bf16* __restrict__ W1T,
    bf16* __restrict__ W2T) {
  const int bid = blockIdx.x;
  if (bid < 4096) {
    const size_t i = ((size_t)bid * 256 + threadIdx.x) * 4;
    const float4 v = *(const float4*)(x + i);
    bf16x4 o;
    o[0] = (bf16)v.x; o[1] = (bf16)v.y; o[2] = (bf16)v.z; o[3] = (bf16)v.w;
    *(bf16x4*)(xb + i) = o;
    return;
  }
  const int t = bid - 4096;
  const float* in;
  bf16* out;
  int in_ld, out_ld, bx, by;
  if (t < 1024) {
    const int q = t >> 8, r = t & 255;
    bx = r & 15; by = r >> 4; in_ld = 512; out_ld = 512;
    in = (q == 0) ? Wq : (q == 1) ? Wk : (q == 2) ? Wv : Wo;
    out = (q == 0) ? WqkvT
          : (q == 1) ? WqkvT + 512 * 512
          : (q == 2) ? WqkvT + 2 * 512 * 512
                     : WoT;
  } else if (t < 2048) {
    const int r = t - 1024;
    bx = r & 63; by = r >> 6; in_ld = 2048; out_ld = 512;
    in = W1; out = W1T;
  } else {
    const int r = t - 2048;
    bx = r & 15; by = r >> 4; in_ld = 512; out_ld = 2048;
    in = W2; out = W2T;
  }
  __shared__ __align__(16) bf16 tl[32][33];
  const int tx = threadIdx.x & 31, ty = threadIdx.x >> 5;
  const int n0 = bx * 32, k0 = by * 32;
#pragma unroll
  for (int i = 0; i < 4; ++i)
    tl[ty + 8 * i][tx] = (bf16)in[(size_t)(k0 + ty + 8 * i) * in_ld + n0 + tx];
  __syncthreads();
#pragma unroll
  for (int i = 0; i < 4; ++i)
    out[(size_t)(n0 + ty + 8 * i) * out_ld + k0 + tx] = tl[tx][ty + 8 * i];
}

extern "C" void kernel_launch(void* const* d_in, const int* in_sizes, int n_in,
                              void* d_out, int out_size, void* d_ws,
                              size_t ws_size, hipStream_t stream) {
  const float* x = (const float*)d_in[0];
  const float* Wq = (const float*)d_in[1];
  const float* Wk = (const float*)d_in[2];
  const float* Wv = (const float*)d_in[3];
  const float* Wo = (const float*)d_in[4];
  const float* W1 = (const float*)d_in[5];
  const float* b1 = (const float*)d_in[6];
  const float* W2 = (const float*)d_in[7];
  const float* b2 = (const float*)d_in[8];
  float* out = (float*)d_out;  // fp32 output

  char* ws = (char*)d_ws;
  size_t off = 0;
  auto alloc = [&](size_t bytes) {
    char* p = ws + off;
    off += (bytes + 255) & ~(size_t)255;
    return p;
  };
  bf16* WqkvT = (bf16*)alloc(1536ULL * 512 * 2);
  bf16* WoT = (bf16*)alloc(512ULL * 512 * 2);
  bf16* W1T = (bf16*)alloc(2048ULL * 512 * 2);
  bf16* W2T = (bf16*)alloc(512ULL * 2048 * 2);
  bf16* xb = (bf16*)alloc(8192ULL * 512 * 2);      // bf16(x); reused as x2
  bf16* QKV = (bf16*)alloc(8192ULL * 1536 * 2);    // [8192][1536]
  bf16* Vt = (bf16*)alloc(32ULL * 64 * 2048 * 2);  // [B*H][64][2048]
  bf16* attn = (bf16*)alloc(8192ULL * 512 * 2);
  bf16* x2 = xb;     // xb dead after QKV gemm
  bf16* hbuf = QKV;  // FFN hidden [8192][2048] = QKV+Vt region (dead by FFN1)

  const dim3 tb(256);
  prep<<<dim3(7168), tb, 0, stream>>>(x, Wq, Wk, Wv, Wo, W1, W2, xb, WqkvT,
                                      WoT, W1T, W2T);
  // QKV gemm also writes V transposed into Vt (V panel blocks n0>=1024).
  gemm_bt<0, bf16, 128><<<dim3(12, 64), tb, 0, stream>>>(
      xb, WqkvT, QKV, nullptr, nullptr, nullptr, Vt, 8192, 1536, 512);
  flash_attn<<<dim3(16, 32), tb, 0, stream>>>(QKV, Vt, attn);
  gemm_bt<1, bf16, 64><<<dim3(8, 64), tb, 0, stream>>>(
      attn, WoT, x2, nullptr, x, nullptr, nullptr, 8192, 512, 512);
  gemm_bt<2, bf16, 128><<<dim3(16, 64), tb, 0, stream>>>(
      x2, W1T, hbuf, b1, nullptr, nullptr, nullptr, 8192, 2048, 512);
  gemm_bt<3, float, 64><<<dim3(8, 64), tb, 0, stream>>>(
      hbuf, W2T, out, b2, nullptr, x2, nullptr, 8192, 512, 2048);
}